// Round 7
// baseline (8398.613 us; speedup 1.0000x reference)
//
#include <hip/hip_runtime.h>
#include <hip/hip_bf16.h>
#include <cstdint>
#include <cstddef>

#define Bdim 256
#define Tdim 256
#define Idim 512
#define Hdim 1024
#define Odim 5
#define BH (Bdim * Hdim)

using short8 = __attribute__((ext_vector_type(8))) short;
using f32x4  = __attribute__((ext_vector_type(4))) float;
typedef unsigned long long u64;

__device__ __forceinline__ short bf16_of(float f) {
  unsigned u = __builtin_bit_cast(unsigned, f);
  u += 0x7fffu + ((u >> 16) & 1u);
  return (short)(u >> 16);
}

__device__ __forceinline__ float sigmf(float x) {
  return 1.0f / (1.0f + __expf(-x));
}

// x fp32 [B][T][I] -> bf16 [T][B][I]  (lane stride 1KB instead of 512KB!)
__global__ __launch_bounds__(256) void k_cvt_x(const float* __restrict__ src,
                                               short* __restrict__ dst) {
  int e = (blockIdx.x * 256 + threadIdx.x) * 8;
  int row = e >> 9;          // b*T + t
  int i0  = e & 511;
  int b = row >> 8, t = row & 255;
  float4 u = *reinterpret_cast<const float4*>(src + e);
  float4 v = *reinterpret_cast<const float4*>(src + e + 4);
  short8 o = {bf16_of(u.x), bf16_of(u.y), bf16_of(u.z), bf16_of(u.w),
              bf16_of(v.x), bf16_of(v.y), bf16_of(v.z), bf16_of(v.w)};
  *reinterpret_cast<short8*>(dst + (((t << 8) + b) << 9) + i0) = o;
}

__global__ __launch_bounds__(256) void k_init(const float* __restrict__ hidden,
    short* __restrict__ h0s0, short* __restrict__ h1s0) {
  int i = blockIdx.x * 256 + threadIdx.x;
  if (i < BH) {
    h0s0[i] = bf16_of(hidden[i]);
    h1s0[i] = bf16_of(hidden[2 * BH + i]);
  }
}

// ---- split-group barrier: 2 layer-groups x 8 virtual-group counters ----
__device__ __forceinline__ void ctr_arrive(unsigned* ctr, int c) {
  __builtin_amdgcn_sched_barrier(0);
  __syncthreads();   // drains vmcnt(0): all agent-scope h-stores at MALL
  if (threadIdx.x == 0)
    __hip_atomic_fetch_add(&ctr[c * 32], 1u, __ATOMIC_RELAXED,
                           __HIP_MEMORY_SCOPE_AGENT);
}

// poll: group0 ctrs (0..7) >= tg0 AND group1 ctrs (8..15) >= tg1 (0 = skip)
__device__ __forceinline__ void ctr_poll2(unsigned* ctr, unsigned tg0, unsigned tg1) {
  if (threadIdx.x < 64) {
    const int lane = threadIdx.x;
    const unsigned tgt = (lane < 8) ? tg0 : (lane < 16 ? tg1 : 0u);
    unsigned* p = ctr + (lane < 16 ? lane : 0) * 32;
    for (;;) {
      bool ok = true;
      if (tgt) {
        unsigned v = __hip_atomic_load(p, __ATOMIC_RELAXED, __HIP_MEMORY_SCOPE_AGENT);
        ok = (v >= tgt);
      }
      if (__all(ok)) break;
      __builtin_amdgcn_s_sleep(1);
    }
  }
}

// ---- 2-deep pipelined GEMM primitives (ping-pong reg buffers A/B) ----
#define LOADBLK(SUF, A0P, A1P, KB)                                             \
  { _Pragma("unroll")                                                          \
    for (int u = 0; u < 8; ++u) {                                              \
      const int k = (KB) + u * 32 + kl;                                        \
      Ar0##SUF[u] = *(const short8*)((A0P) + k);                               \
      Ar1##SUF[u] = *(const short8*)((A1P) + k);                               \
      Br0##SUF[u] = *(const short8*)(lb0 + k);                                 \
      Br1##SUF[u] = *(const short8*)(lb1 + k);                                 \
    } }

#define MFMABLK(SUF)                                                           \
  { _Pragma("unroll")                                                          \
    for (int u = 0; u < 8; ++u) {                                              \
      acc[0][0] = __builtin_amdgcn_mfma_f32_16x16x32_bf16(Ar0##SUF[u], Br0##SUF[u], acc[0][0], 0, 0, 0); \
      acc[1][0] = __builtin_amdgcn_mfma_f32_16x16x32_bf16(Ar1##SUF[u], Br0##SUF[u], acc[1][0], 0, 0, 0); \
      acc[0][1] = __builtin_amdgcn_mfma_f32_16x16x32_bf16(Ar0##SUF[u], Br1##SUF[u], acc[0][1], 0, 0, 0); \
      acc[1][1] = __builtin_amdgcn_mfma_f32_16x16x32_bf16(Ar1##SUF[u], Br1##SUF[u], acc[1][1], 0, 0, 0); \
    } }

// 4-block segment, 2-deep: 32 loads in flight during MFMAs
#define GEMM_SEG4(P0, P1, KB)                                                  \
  LOADBLK(A, P0, P1, (KB))                                                     \
  LOADBLK(B, P0, P1, (KB) + 256)                                               \
  MFMABLK(A)                                                                   \
  LOADBLK(A, P0, P1, (KB) + 512)                                               \
  MFMABLK(B)                                                                   \
  LOADBLK(B, P0, P1, (KB) + 768)                                               \
  MFMABLK(A)                                                                   \
  MFMABLK(B)

// fp32 x fallback (only if ws too small for xb16): 4-deep load+cvt
#define GEMM_X(XF0, XF1)                                                       \
  for (int blk = 0; blk < 4; ++blk) {                                          \
    f32x4 U0[4][2], U1[4][2]; short8 Bx0[4], Bx1[4];                           \
    const int kb = Hdim + blk * 128 + kl;                                      \
    _Pragma("unroll")                                                          \
    for (int u = 0; u < 4; ++u) {                                              \
      const int k = kb + u * 32;                                               \
      U0[u][0] = *(const f32x4*)((XF0) + k);                                   \
      U0[u][1] = *(const f32x4*)((XF0) + k + 4);                               \
      U1[u][0] = *(const f32x4*)((XF1) + k);                                   \
      U1[u][1] = *(const f32x4*)((XF1) + k + 4);                               \
      Bx0[u] = *(const short8*)(lb0 + k);                                      \
      Bx1[u] = *(const short8*)(lb1 + k);                                      \
    }                                                                          \
    _Pragma("unroll")                                                          \
    for (int u = 0; u < 4; ++u) {                                              \
      short8 a0 = {bf16_of(U0[u][0][0]), bf16_of(U0[u][0][1]), bf16_of(U0[u][0][2]), bf16_of(U0[u][0][3]), \
                   bf16_of(U0[u][1][0]), bf16_of(U0[u][1][1]), bf16_of(U0[u][1][2]), bf16_of(U0[u][1][3])}; \
      short8 a1 = {bf16_of(U1[u][0][0]), bf16_of(U1[u][0][1]), bf16_of(U1[u][0][2]), bf16_of(U1[u][0][3]), \
                   bf16_of(U1[u][1][0]), bf16_of(U1[u][1][1]), bf16_of(U1[u][1][2]), bf16_of(U1[u][1][3])}; \
      acc[0][0] = __builtin_amdgcn_mfma_f32_16x16x32_bf16(a0, Bx0[u], acc[0][0], 0, 0, 0); \
      acc[1][0] = __builtin_amdgcn_mfma_f32_16x16x32_bf16(a1, Bx0[u], acc[1][0], 0, 0, 0); \
      acc[0][1] = __builtin_amdgcn_mfma_f32_16x16x32_bf16(a0, Bx1[u], acc[0][1], 0, 0, 0); \
      acc[1][1] = __builtin_amdgcn_mfma_f32_16x16x32_bf16(a1, Bx1[u], acc[1][1], 0, 0, 0); \
    }                                                                          \
  }

// Persistent weight-stationary LSTM; write-once h-seq buffers; split per-layer
// sync. Round r: L0 computes h0(t=r) (slot r -> r+1); L1 computes h1(t=r)
// reading h1seq[r%D] (own, gated ctrL1>=16r) + h0seq[(r+1)%D] (gated
// ctrL0>=16(r+1)). L1's own-h GEMM overlaps L0's tail via split polls.
__global__ __launch_bounds__(512, 1) void k_persist(
    const float* __restrict__ W0, const float* __restrict__ b0v,
    const float* __restrict__ W1, const float* __restrict__ b1v,
    const float* __restrict__ hidden,
    const float* __restrict__ xf,     // fp32 [B][T][I] (fallback)
    const short* __restrict__ xbt,    // bf16 [T][B][I] (preferred)
    int useXb,
    short* __restrict__ h0seq,        // [D][B][H] bf16
    short* __restrict__ h1seq,        // [D][B][H] bf16
    float* __restrict__ finals,       // [L][2][B][H] fp32 (in d_out)
    unsigned* __restrict__ ctr, int D) {
  extern __shared__ short lw[];       // [32][pitch] bf16 weight slice
  const int tid  = threadIdx.x;
  const int wg   = blockIdx.x;
  const bool isL0 = (wg < 128);
  const int slot  = isL0 ? wg : wg - 128;
  const int hcol0 = slot * 8;
  const int K     = isL0 ? (Hdim + Idim) : (2 * Hdim);
  const int pitch = K + 8;
  const int layer = isL0 ? 0 : 1;
  const int myc   = layer * 8 + (wg & 7);
  const int lead  = (D > 4) ? (D - 2) : 2;   // max L0 run-ahead (slots safe)
  const float* Wsrc = isL0 ? W0 : W1;
  const float* bsrc = isL0 ? b0v : b1v;

  // stage weight slice into LDS (fp32 -> bf16), rows r = gate*8 + hcol
  for (int r = 0; r < 32; ++r) {
    const float* src = Wsrc + (size_t)((r >> 3) * Hdim + hcol0 + (r & 7)) * K;
    short* dst = lw + r * pitch;
    for (int k = tid; k < K; k += 512) dst[k] = bf16_of(src[k]);
  }

  const int lane = tid & 63;
  const int wv   = tid >> 6;
  const int col  = lane & 15;
  const int rg   = lane >> 4;
  const int kl   = rg * 8;
  const int row0 = wv * 32 + col;

  float biasv[2];
  #pragma unroll
  for (int n = 0; n < 2; ++n)
    biasv[n] = bsrc[(n * 2 + (col >= 8 ? 1 : 0)) * Hdim + hcol0 + (col & 7)];

  float creg[2][4], hfin[2][4];
  #pragma unroll
  for (int m = 0; m < 2; ++m)
    #pragma unroll
    for (int j = 0; j < 4; ++j) {
      int b = wv * 32 + m * 16 + rg * 4 + j;
      creg[m][j] = hidden[(layer * 2 + 1) * BH + b * Hdim + hcol0 + (col & 7)];
      hfin[m][j] = 0.f;
    }

  // launch-start acquire: one L2/L1 inv per WG per launch (replay staleness)
  if (tid == 0)
    (void)__hip_atomic_load(ctr, __ATOMIC_ACQUIRE, __HIP_MEMORY_SCOPE_AGENT);
  __syncthreads();

  const short* lb0 = lw + col * pitch;          // N-tile 0: gates f,i
  const short* lb1 = lw + (16 + col) * pitch;   // N-tile 1: gates g,o

  int i_cur = 0;                                // r % D
  for (int r = 0; r < 256; ++r) {
    const int i_next = (i_cur + 1 == D) ? 0 : i_cur + 1;
    f32x4 acc[2][2] = {};
    short8 Ar0A[8], Ar1A[8], Br0A[8], Br1A[8];
    short8 Ar0B[8], Ar1B[8], Br0B[8], Br1B[8];
    short* hout;

    if (isL0) {
      // x-part first (independent of recurrence) — hides poll latency
      if (useXb) {
        const short* xa = xbt + (size_t)r * (Bdim * Idim) + row0 * Idim - Hdim;
        const short* xc = xa + 16 * Idim;
        LOADBLK(A, xa, xc, 1024)
        LOADBLK(B, xa, xc, 1280)
        MFMABLK(A)
        MFMABLK(B)
      } else {
        const float* xf0 = xf + (size_t)(row0 * Tdim + r) * Idim - Hdim;
        const float* xf1 = xf + (size_t)((row0 + 16) * Tdim + r) * Idim - Hdim;
        GEMM_X(xf0, xf1)
      }
      __builtin_amdgcn_sched_barrier(0);
      unsigned tg1 = (r > lead) ? 16u * (unsigned)(r - lead) : 0u;
      if (r > 0 || tg1) ctr_poll2(ctr, 16u * (unsigned)r, tg1);
      if (tid == 0 && r > 0 && i_cur == 0)  // wrap inv: once per D rounds
        (void)__hip_atomic_load(ctr, __ATOMIC_ACQUIRE, __HIP_MEMORY_SCOPE_AGENT);
      __syncthreads();
      const short* ah = h0seq + (size_t)i_cur * BH + row0 * Hdim;
      GEMM_SEG4(ah, ah + 16 * Hdim, 0)
      hout = h0seq + (size_t)i_next * BH;
    } else {
      // phase 1: own-h GEMM, gated only on ctrL1 (overlaps L0's tail)
      if (r > 0) ctr_poll2(ctr, 0u, 16u * (unsigned)r);
      if (tid == 0 && r > 0 && i_cur == 0)  // wrap inv before recycled reads
        (void)__hip_atomic_load(ctr, __ATOMIC_ACQUIRE, __HIP_MEMORY_SCOPE_AGENT);
      __syncthreads();
      const short* ah = h1seq + (size_t)i_cur * BH + row0 * Hdim;
      GEMM_SEG4(ah, ah + 16 * Hdim, 0)
      __builtin_amdgcn_sched_barrier(0);
      // phase 2: h0(t=r) part, gated on L0 finishing round r
      ctr_poll2(ctr, 16u * (unsigned)(r + 1), 0u);
      __syncthreads();
      const short* ax = h0seq + (size_t)i_next * BH + row0 * Hdim - Hdim;
      GEMM_SEG4(ax, ax + 16 * Hdim, 1024)
      hout = h1seq + (size_t)i_next * BH;
    }

    // fused gates: D row = rg*4+j -> batch; lanes col<8 own h-col hcol0+col
    #pragma unroll
    for (int m = 0; m < 2; ++m) {
      #pragma unroll
      for (int j = 0; j < 4; ++j) {
        float fi  = acc[m][0][j] + biasv[0];
        float go  = acc[m][1][j] + biasv[1];
        float iv_ = __shfl_xor(fi, 8, 64);
        float ov_ = __shfl_xor(go, 8, 64);
        float fv = sigmf(fi), iv = sigmf(iv_);
        float gv = tanhf(go), ov = sigmf(ov_);
        float cn = fv * creg[m][j] + iv * gv;
        creg[m][j] = cn;
        float hn = ov * tanhf(cn);
        hfin[m][j] = hn;
        // pack 4 consecutive h-cols into one 8B agent-scope (MALL) store
        unsigned hv = (unsigned)(unsigned short)bf16_of(hn);
        unsigned p1 = hv | ((unsigned)__shfl_xor((int)hv, 1, 64) << 16);
        u64 p2 = (u64)p1 | ((u64)(unsigned)__shfl_xor((int)p1, 2, 64) << 32);
        if ((col & 3) == 0 && col < 8) {
          int b = wv * 32 + m * 16 + rg * 4 + j;
          __hip_atomic_store((u64*)(hout + b * Hdim + hcol0 + col), p2,
                             __ATOMIC_RELAXED, __HIP_MEMORY_SCOPE_AGENT);
        }
      }
    }
    ctr_arrive(ctr, myc);
    i_cur = i_next;
  }

  // epilogue: finals [L][2][B][H]
  if (col < 8) {
    #pragma unroll
    for (int m = 0; m < 2; ++m)
      #pragma unroll
      for (int j = 0; j < 4; ++j) {
        int b = wv * 32 + m * 16 + rg * 4 + j;
        finals[(layer * 2 + 0) * BH + b * Hdim + hcol0 + col] = hfin[m][j];
        finals[(layer * 2 + 1) * BH + b * Hdim + hcol0 + col] = creg[m][j];
      }
  }
}

__global__ __launch_bounds__(256) void k_outproj(const float* __restrict__ h1f,
    const float* __restrict__ Wout, const float* __restrict__ bout,
    float* __restrict__ out) {
  int b = blockIdx.x;
  int tid = threadIdx.x;
  float hv[4];
  #pragma unroll
  for (int j = 0; j < 4; ++j) hv[j] = h1f[b * Hdim + tid + j * 256];
  __shared__ float red[Odim][4];
  #pragma unroll
  for (int o = 0; o < Odim; ++o) {
    float p = 0.f;
    #pragma unroll
    for (int j = 0; j < 4; ++j) p += hv[j] * Wout[o * Hdim + tid + j * 256];
    #pragma unroll
    for (int s = 32; s > 0; s >>= 1) p += __shfl_down(p, s, 64);
    if ((tid & 63) == 0) red[o][tid >> 6] = p;
  }
  __syncthreads();
  if (tid < Odim)
    out[b * Odim + tid] = red[tid][0] + red[tid][1] + red[tid][2] + red[tid][3] + bout[tid];
}

extern "C" void kernel_launch(void* const* d_in, const int* in_sizes, int n_in,
                              void* d_out, int out_size, void* d_ws, size_t ws_size,
                              hipStream_t stream) {
  const float* x      = (const float*)d_in[0];
  const float* hidden = (const float*)d_in[1];
  const float* W0     = (const float*)d_in[2];
  const float* b0     = (const float*)d_in[3];
  const float* W1     = (const float*)d_in[4];
  const float* b1     = (const float*)d_in[5];
  const float* Wout   = (const float*)d_in[6];
  const float* bout   = (const float*)d_in[7];
  float* out = (float*)d_out;
  float* finals = out + Bdim * Odim;

  char* ws = (char*)d_ws;
  size_t off = 0;
  auto alloc = [&](size_t bytes) {
    void* p = ws + off;
    off += (bytes + 255) & ~(size_t)255;
    return p;
  };
  unsigned* ctr = (unsigned*)alloc(16 * 32 * sizeof(unsigned));
  const size_t seqSlot = (size_t)BH * 2;                     // 0.5 MB
  const size_t xbBytes = (size_t)Tdim * Bdim * Idim * 2;     // 67.1 MB
  int useXb = 0;
  short* xbt = nullptr;
  if (ws_size > off + xbBytes + 8 * 2 * seqSlot + (1 << 20)) {  // need D>=8
    useXb = 1;
    xbt = (short*)alloc(xbBytes);
  }
  size_t avail = (ws_size > off + 512) ? (ws_size - off - 512) : 0;
  int D = (int)(avail / (2 * seqSlot));
  if (D > 257) D = 257;
  if (D < 4) D = 4;
  short* h0seq = (short*)alloc((size_t)D * seqSlot);
  short* h1seq = (short*)alloc((size_t)D * seqSlot);

  if (useXb)
    k_cvt_x<<<(Tdim * Bdim * Idim) / (256 * 8), 256, 0, stream>>>(x, xbt);
  k_init<<<BH / 256, 256, 0, stream>>>(hidden, h0seq, h1seq);
  hipMemsetAsync(ctr, 0, 16 * 32 * sizeof(unsigned), stream);

  const int ldsBytes = 32 * (2 * Hdim + 8) * 2;  // 131584 (L1 slice, the max)
  hipFuncSetAttribute((const void*)k_persist,
                      hipFuncAttributeMaxDynamicSharedMemorySize, ldsBytes);
  void* args[] = {(void*)&W0, (void*)&b0, (void*)&W1, (void*)&b1,
                  (void*)&hidden, (void*)&x, (void*)&xbt, (void*)&useXb,
                  (void*)&h0seq, (void*)&h1seq,
                  (void*)&finals, (void*)&ctr, (void*)&D};
  hipLaunchCooperativeKernel((const void*)k_persist, dim3(256), dim3(512),
                             args, ldsBytes, stream);

  k_outproj<<<Bdim, 256, 0, stream>>>(finals + 2 * BH, Wout, bout, out);
}